// Round 13
// baseline (473.079 us; speedup 1.0000x reference)
//
#include <hip/hip_runtime.h>
#include <hip/hip_bf16.h>
#include <cstdint>
#include <cstddef>

#define BN_EPS 1e-5f
typedef long long ll;
using bf16x8 = __attribute__((ext_vector_type(8))) short;
using f32x4  = __attribute__((ext_vector_type(4))) float;

__device__ __forceinline__ unsigned short f2bf(float f) {
    union { float f; unsigned u; } c; c.f = f;
    unsigned u = c.u;
    u += 0x7fff + ((u >> 16) & 1);   // round-to-nearest-even
    return (unsigned short)(u >> 16);
}
__device__ __forceinline__ float bf2f(unsigned h) {
    union { unsigned u; float f; } c; c.u = h << 16;
    return c.f;
}
__device__ __forceinline__ void addbf4(float* a, uint2 v) {
    a[0] += bf2f(v.x & 0xffffu); a[1] += bf2f(v.x >> 16);
    a[2] += bf2f(v.y & 0xffffu); a[3] += bf2f(v.y >> 16);
}
__device__ __forceinline__ float4 bf4_to_f4(uint2 v) {
    return make_float4(bf2f(v.x & 0xffffu), bf2f(v.x >> 16),
                       bf2f(v.y & 0xffffu), bf2f(v.y >> 16));
}
// Async global->LDS, 16B per lane. LDS base must be wave-uniform; HW writes
// lane i's 16B at base + i*16.
__device__ __forceinline__ void gload_lds16(const void* g, void* lds) {
    __builtin_amdgcn_global_load_lds(
        (const __attribute__((address_space(1))) unsigned int*)g,
        (__attribute__((address_space(3))) unsigned int*)lds, 16, 0, 0);
}

// ---------------------------------------------------------------------------
// detect (block 0) + init, merged.
__global__ void build0_kernel(const int* ei32, int* flag, int* deg, int* cursor, int N) {
    int i = blockIdx.x * 256 + threadIdx.x;
    if (i < N) { deg[i] = 1; cursor[i] = 0; }   // deg starts at 1 (self loop)
    if (blockIdx.x == 0) {
        __shared__ int any;
        if (threadIdx.x == 0) any = 0;
        __syncthreads();
        for (int t = threadIdx.x; t < 2048; t += 256)
            if (ei32[2 * t + 1] != 0) any = 1;
        __syncthreads();
        if (threadIdx.x == 0) *flag = (any == 0) ? 1 : 0;
    }
}

__global__ void count_kernel(const void* ei, int E, int* deg, const int* flag) {
    int e = blockIdx.x * 256 + threadIdx.x;
    if (e >= E) return;
    int d = (*flag) ? (int)((const ll*)ei)[(size_t)E + e]
                    : ((const int*)ei)[(size_t)E + e];
    atomicAdd(&deg[d], 1);
}

// Block-level inclusive scan of (deg[i]-1); bsum[b] = block total; also dis.
__global__ __launch_bounds__(1024) void scanA_kernel(const int* deg, int* row_ptr,
                                                     int* bsum, float* dis, int N) {
    __shared__ int wsum[16];
    int i = blockIdx.x * 1024 + threadIdx.x;
    int lane = threadIdx.x & 63, wid = threadIdx.x >> 6;
    int dv = (i < N) ? deg[i] : 1;
    if (i < N) dis[i] = rsqrtf((float)dv);
    int v = (i < N) ? (dv - 1) : 0;
    int s = v;
#pragma unroll
    for (int o = 1; o < 64; o <<= 1) { int t = __shfl_up(s, o); if (lane >= o) s += t; }
    if (lane == 63) wsum[wid] = s;
    __syncthreads();
    if (threadIdx.x < 16) {
        int w = wsum[threadIdx.x];
        int ws_ = w;
#pragma unroll
        for (int o = 1; o < 16; o <<= 1) { int t = __shfl_up(ws_, o); if ((int)threadIdx.x >= o) ws_ += t; }
        wsum[threadIdx.x] = ws_ - w;  // exclusive wave offset
    }
    __syncthreads();
    s += wsum[wid];
    if (i < N) row_ptr[i + 1] = s;
    if (threadIdx.x == 1023) bsum[blockIdx.x] = s;
}

__global__ void scanB_kernel(int* bsum, int nb) {
    int lane = threadIdx.x;
    int v = (lane < nb) ? bsum[lane] : 0;
    int s = v;
#pragma unroll
    for (int o = 1; o < 64; o <<= 1) { int t = __shfl_up(s, o); if (lane >= o) s += t; }
    if (lane < nb) bsum[lane] = s - v;  // exclusive block offsets
}

__global__ __launch_bounds__(1024) void scanC_kernel(int* row_ptr, const int* bsum, int N) {
    int i = blockIdx.x * 1024 + threadIdx.x;
    if (i < N) row_ptr[i + 1] += bsum[blockIdx.x];
    if (i == 0) row_ptr[0] = 0;
}

__global__ void fill_kernel(const void* ei, int E, const int* row_ptr,
                            int* cursor, int* csr, const int* flag) {
    int e = blockIdx.x * 256 + threadIdx.x;
    if (e >= E) return;
    int s, d;
    if (*flag) { const ll* p = (const ll*)ei; s = (int)p[e]; d = (int)p[(size_t)E + e]; }
    else       { const int* p = (const int*)ei; s = p[e]; d = p[(size_t)E + e]; }
    int pos = atomicAdd(&cursor[d], 1);
    csr[row_ptr[d] + pos] = s;
}

// ---------------------------------------------------------------------------
struct LayerP {
    const float *W, *g, *b, *m, *v;
    int K, Dout, ncb, boff;
};
struct LayerPs { LayerP l[5]; };

// Merged fold: blockIdx.x<128 -> B-fragment packing; >=128 -> cvec.
// B fragment: lane l, slot i holds W'[kc*32 + 8*(l>>4) + i][cb*16 + (l&15)].
__global__ __launch_bounds__(256) void fold_all(LayerPs P,
                                                unsigned short* __restrict__ Bhi,
                                                unsigned short* __restrict__ Blo,
                                                float* __restrict__ cvecA) {
    const LayerP& L = P.l[blockIdx.y];
    if (blockIdx.x < 128) {
        int nkc = (L.K + 63) >> 6 << 1;   // chunks padded to BK=64 pairs
        int total = nkc * L.ncb * 512;
        int idx = blockIdx.x * 256 + threadIdx.x;
        if (idx >= total) return;
        int i = idx & 7;
        int lane = (idx >> 3) & 63;
        int cb = (idx >> 9) % L.ncb;
        int kc = (idx >> 9) / L.ncb;
        int k = kc * 32 + (lane >> 4) * 8 + i;
        int col = cb * 16 + (lane & 15);
        float val = 0.f;
        if (k < L.K && col < L.Dout) {
            float s = L.g[k] * rsqrtf(L.v[k] + BN_EPS);
            val = L.W[k * L.Dout + col] * s;
        }
        unsigned short h = f2bf(val);
        Bhi[L.boff + idx] = h;
        Blo[L.boff + idx] = f2bf(val - bf2f(h));
    } else {
        int wid = threadIdx.x >> 6, lane = threadIdx.x & 63;
        int col = (blockIdx.x - 128) * 4 + wid;
        float acc = 0.f;
        if (col < L.Dout) {
            for (int k = lane; k < L.K; k += 64) {
                float s = L.g[k] * rsqrtf(L.v[k] + BN_EPS);
                acc += (L.b[k] - L.m[k] * s) * L.W[k * L.Dout + col];
            }
        }
#pragma unroll
        for (int o = 32; o >= 1; o >>= 1) acc += __shfl_xor(acc, o);
        if (lane == 0 && col < 128) cvecA[128 * blockIdx.y + col] = (col < L.Dout) ? acc : 0.f;
    }
}

// ---------------------------------------------------------------------------
// Dout=128 all-bf16 GEMM, 2-phase double-buffered staging (counted vmcnt,
// raw s_barrier — stage k+1's loads stay in flight across the barrier).
// Wave w owns col-blocks {2w,2w+1} over all 64 rows.
__global__ __launch_bounds__(256, 4) void gemm_bf2_kernel(
    const unsigned short* __restrict__ X1, int K1, int ld1,
    const unsigned short* __restrict__ X2, int ld2,
    const unsigned short* __restrict__ Bhi, const unsigned short* __restrict__ Blo,
    const float* __restrict__ cvec, const float* __restrict__ dis,
    unsigned short* __restrict__ outp, int K, int N)
{
    __shared__ unsigned short Xs[2][64 * 64];   // 2 x 8KB, linear [row][slot*8]
    const int tid = threadIdx.x;
    const int w = tid >> 6, lane = tid & 63;
    const int lr = lane & 15, lg = lane >> 4;
    const int brow = blockIdx.x * 64;
    const int nkt = (K + 63) >> 6;
    const int cb0 = 2 * w;

    int s_r[2], s_sl[2];
#pragma unroll
    for (int p = 0; p < 2; ++p) {
        int idx = p * 256 + tid;
        s_r[p] = idx >> 3;
        s_sl[p] = idx & 7;
    }

    auto STAGE = [&](int kt, int b) {
        const int k0 = kt * 64;
        const unsigned short* T = (k0 < K1) ? X1 : X2;
        const int ldT = (k0 < K1) ? ld1 : ld2;
        const int kb = (k0 < K1) ? k0 : (k0 - K1);
#pragma unroll
        for (int p = 0; p < 2; ++p) {
            int grow = brow + s_r[p]; if (grow >= N) grow = N - 1;
            int ksl = s_sl[p] ^ (s_r[p] & 7);    // source slot pre-swizzle
            gload_lds16(T + (size_t)grow * ldT + kb + ksl * 8,
                        (char*)Xs[b] + (size_t)(p * 256 + w * 64) * 16);
        }
    };

    f32x4 acc[4][2];
#pragma unroll
    for (int c = 0; c < 2; ++c) {
        float cv = cvec[(cb0 + c) * 16 + lr];
        f32x4 iv = {cv, cv, cv, cv};
#pragma unroll
        for (int rb = 0; rb < 4; ++rb) acc[rb][c] = iv;
    }

    STAGE(0, 0);
    for (int kt = 0; kt < nkt; ++kt) {
        const int cur = kt & 1;
        if (kt + 1 < nkt) STAGE(kt + 1, cur ^ 1);
        __builtin_amdgcn_sched_barrier(0);
        if (kt + 1 < nkt) asm volatile("s_waitcnt vmcnt(2)" ::: "memory");
        else              asm volatile("s_waitcnt vmcnt(0)" ::: "memory");
        __builtin_amdgcn_s_barrier();
        __builtin_amdgcn_sched_barrier(0);

#pragma unroll
        for (int ks = 0; ks < 2; ++ks) {
            const int kcg = kt * 2 + ks;
            bf16x8 a[4];
#pragma unroll
            for (int rb = 0; rb < 4; ++rb) {
                int r = rb * 16 + lr;
                a[rb] = *(const bf16x8*)((const char*)Xs[cur] + r * 128 +
                                         ((ks * 64 + lg * 16) ^ ((r & 7) << 4)));
            }
            const bf16x8* bh = (const bf16x8*)Bhi + (size_t)kcg * 8 * 64;
            const bf16x8* bl = (const bf16x8*)Blo + (size_t)kcg * 8 * 64;
#pragma unroll
            for (int c = 0; c < 2; ++c) {
                bf16x8 bhf = bh[(cb0 + c) * 64 + lane];
                bf16x8 blf = bl[(cb0 + c) * 64 + lane];
#pragma unroll
                for (int rb = 0; rb < 4; ++rb) {
                    acc[rb][c] = __builtin_amdgcn_mfma_f32_16x16x32_bf16(a[rb], bhf, acc[rb][c], 0, 0, 0);
                    acc[rb][c] = __builtin_amdgcn_mfma_f32_16x16x32_bf16(a[rb], blf, acc[rb][c], 0, 0, 0);
                }
            }
        }
        asm volatile("s_waitcnt lgkmcnt(0)" ::: "memory");
        __builtin_amdgcn_s_barrier();
        __builtin_amdgcn_sched_barrier(0);
    }

    // D lane map: row = (lane>>4)*4 + reg, col = lane&15
#pragma unroll
    for (int rb = 0; rb < 4; ++rb) {
#pragma unroll
        for (int r = 0; r < 4; ++r) {
            int grow = brow + rb * 16 + lg * 4 + r;
            if (grow >= N) continue;
            float d = dis[grow];
#pragma unroll
            for (int c = 0; c < 2; ++c)
                outp[(size_t)grow * 128 + (cb0 + c) * 16 + lr] = f2bf(d * acc[rb][c][r]);
        }
    }
}

// Dout=128 mixed GEMM: stage hi/lo bf16 planes in LDS (split done once at
// staging), inner loop = bf2 + optional lo-MFMA. B1/B2: source is bf16.
template <bool B1, bool B2>
__global__ __launch_bounds__(256, 3) void gemm_mix2_kernel(
    const void* __restrict__ X1, int K1, int ld1,
    const void* __restrict__ X2, int ld2,
    const unsigned short* __restrict__ Bhi, const unsigned short* __restrict__ Blo,
    const float* __restrict__ cvec, const float* __restrict__ dis,
    unsigned short* __restrict__ outp, int K, int kc_lo, int N)
{
    __shared__ unsigned short Xhi[64 * 64];
    __shared__ unsigned short Xlo[64 * 64];
    const int tid = threadIdx.x;
    const int w = tid >> 6, lane = tid & 63;
    const int lr = lane & 15, lg = lane >> 4;
    const int brow = blockIdx.x * 64;
    const int nkt = (K + 63) >> 6;
    const int cb0 = 2 * w;

    f32x4 acc[4][2];
#pragma unroll
    for (int c = 0; c < 2; ++c) {
        float cv = cvec[(cb0 + c) * 16 + lr];
        f32x4 iv = {cv, cv, cv, cv};
#pragma unroll
        for (int rb = 0; rb < 4; ++rb) acc[rb][c] = iv;
    }

    for (int kt = 0; kt < nkt; ++kt) {
        const int k0 = kt * 64;
        const bool kt_lo = (kt * 2 + 1) >= kc_lo;   // this kt has fp32 source
#pragma unroll
        for (int p = 0; p < 4; ++p) {
            int fidx = (p * 256 + tid) * 4;
            int r = fidx >> 6;
            int c = fidx & 63;
            int grow = brow + r;
            int k = k0 + c;
            float4 val = make_float4(0.f, 0.f, 0.f, 0.f);
            if (grow < N) {
                if (k < K1) {
                    if (B1) val = bf4_to_f4(*(const uint2*)((const unsigned short*)X1 + (size_t)grow * ld1 + k));
                    else    val = *(const float4*)((const float*)X1 + (size_t)grow * ld1 + k);
                } else if (k < K) {
                    int kk = k - K1;
                    if (B2) val = bf4_to_f4(*(const uint2*)((const unsigned short*)X2 + (size_t)grow * ld2 + kk));
                    else    val = *(const float4*)((const float*)X2 + (size_t)grow * ld2 + kk);
                }
            }
            unsigned short h0 = f2bf(val.x), h1 = f2bf(val.y),
                           h2 = f2bf(val.z), h3 = f2bf(val.w);
            int b8 = c * 2;
            int addr = r * 128 + (((b8 & 0x70) ^ ((r & 7) << 4)) | (b8 & 8));
            *(uint2*)((char*)Xhi + addr) =
                make_uint2((unsigned)h0 | ((unsigned)h1 << 16),
                           (unsigned)h2 | ((unsigned)h3 << 16));
            if (kt_lo) {
                unsigned short l0 = f2bf(val.x - bf2f(h0)), l1 = f2bf(val.y - bf2f(h1)),
                               l2 = f2bf(val.z - bf2f(h2)), l3 = f2bf(val.w - bf2f(h3));
                *(uint2*)((char*)Xlo + addr) =
                    make_uint2((unsigned)l0 | ((unsigned)l1 << 16),
                               (unsigned)l2 | ((unsigned)l3 << 16));
            }
        }
        __syncthreads();

#pragma unroll
        for (int ks = 0; ks < 2; ++ks) {
            const int kcg = kt * 2 + ks;
            const bool need_lo = (kcg >= kc_lo);
            bf16x8 ah[4], al[4];
#pragma unroll
            for (int rb = 0; rb < 4; ++rb) {
                int r = rb * 16 + lr;
                int off = ((ks * 64 + lg * 16) ^ ((r & 7) << 4));
                ah[rb] = *(const bf16x8*)((const char*)Xhi + r * 128 + off);
                if (need_lo) al[rb] = *(const bf16x8*)((const char*)Xlo + r * 128 + off);
            }
            const bf16x8* bh = (const bf16x8*)Bhi + (size_t)kcg * 8 * 64;
            const bf16x8* bl = (const bf16x8*)Blo + (size_t)kcg * 8 * 64;
#pragma unroll
            for (int c = 0; c < 2; ++c) {
                bf16x8 bhf = bh[(cb0 + c) * 64 + lane];
                bf16x8 blf = bl[(cb0 + c) * 64 + lane];
#pragma unroll
                for (int rb = 0; rb < 4; ++rb) {
                    acc[rb][c] = __builtin_amdgcn_mfma_f32_16x16x32_bf16(ah[rb], bhf, acc[rb][c], 0, 0, 0);
                    acc[rb][c] = __builtin_amdgcn_mfma_f32_16x16x32_bf16(ah[rb], blf, acc[rb][c], 0, 0, 0);
                    if (need_lo)
                        acc[rb][c] = __builtin_amdgcn_mfma_f32_16x16x32_bf16(al[rb], bhf, acc[rb][c], 0, 0, 0);
                }
            }
        }
        __syncthreads();
    }

#pragma unroll
    for (int rb = 0; rb < 4; ++rb) {
#pragma unroll
        for (int r = 0; r < 4; ++r) {
            int grow = brow + rb * 16 + lg * 4 + r;
            if (grow >= N) continue;
            float d = dis[grow];
#pragma unroll
            for (int c = 0; c < 2; ++c)
                outp[(size_t)grow * 128 + (cb0 + c) * 16 + lr] = f2bf(d * acc[rb][c][r]);
        }
    }
}

// Dout=40 all-bf16 GEMM (L5): wave per 16 rows, all 3 col-blocks,
// same 2-phase double-buffered staging as bf2.
__global__ __launch_bounds__(256, 4) void gemm_bf40_kernel(
    const unsigned short* __restrict__ X1, int K1, int ld1,
    const unsigned short* __restrict__ X2, int ld2,
    const unsigned short* __restrict__ Bhi, const unsigned short* __restrict__ Blo,
    const float* __restrict__ cvec, const float* __restrict__ dis,
    unsigned short* __restrict__ outp, int K, int N)
{
    __shared__ unsigned short Xs[2][64 * 64];
    const int tid = threadIdx.x;
    const int w = tid >> 6, lane = tid & 63;
    const int lr = lane & 15, lg = lane >> 4;
    const int brow = blockIdx.x * 64;
    const int nkt = (K + 63) >> 6;

    int s_r[2], s_sl[2];
#pragma unroll
    for (int p = 0; p < 2; ++p) {
        int idx = p * 256 + tid;
        s_r[p] = idx >> 3;
        s_sl[p] = idx & 7;
    }
    auto STAGE = [&](int kt, int b) {
        const int k0 = kt * 64;
        const unsigned short* T = (k0 < K1) ? X1 : X2;
        const int ldT = (k0 < K1) ? ld1 : ld2;
        const int kb = (k0 < K1) ? k0 : (k0 - K1);
#pragma unroll
        for (int p = 0; p < 2; ++p) {
            int grow = brow + s_r[p]; if (grow >= N) grow = N - 1;
            int ksl = s_sl[p] ^ (s_r[p] & 7);
            gload_lds16(T + (size_t)grow * ldT + kb + ksl * 8,
                        (char*)Xs[b] + (size_t)(p * 256 + w * 64) * 16);
        }
    };

    f32x4 acc[3];
#pragma unroll
    for (int cb = 0; cb < 3; ++cb) {
        float cv = cvec[cb * 16 + lr];
        f32x4 iv = {cv, cv, cv, cv};
        acc[cb] = iv;
    }

    STAGE(0, 0);
    for (int kt = 0; kt < nkt; ++kt) {
        const int cur = kt & 1;
        if (kt + 1 < nkt) STAGE(kt + 1, cur ^ 1);
        __builtin_amdgcn_sched_barrier(0);
        if (kt + 1 < nkt) asm volatile("s_waitcnt vmcnt(2)" ::: "memory");
        else              asm volatile("s_waitcnt vmcnt(0)" ::: "memory");
        __builtin_amdgcn_s_barrier();
        __builtin_amdgcn_sched_barrier(0);

        const int r = w * 16 + lr;
        const char* base = (const char*)Xs[cur] + r * 128;
        const int swz = (r & 7) << 4;
        bf16x8 a0 = *(const bf16x8*)(base + ((lg * 16) ^ swz));
        bf16x8 a1 = *(const bf16x8*)(base + ((64 + lg * 16) ^ swz));
#pragma unroll
        for (int ks = 0; ks < 2; ++ks) {
            const int kcg = kt * 2 + ks;
            const bf16x8 af = ks ? a1 : a0;
            const bf16x8* bh = (const bf16x8*)Bhi + (size_t)kcg * 3 * 64;
            const bf16x8* bl = (const bf16x8*)Blo + (size_t)kcg * 3 * 64;
#pragma unroll
            for (int cb = 0; cb < 3; ++cb) {
                bf16x8 bhf = bh[cb * 64 + lane];
                bf16x8 blf = bl[cb * 64 + lane];
                acc[cb] = __builtin_amdgcn_mfma_f32_16x16x32_bf16(af, bhf, acc[cb], 0, 0, 0);
                acc[cb] = __builtin_amdgcn_mfma_f32_16x16x32_bf16(af, blf, acc[cb], 0, 0, 0);
            }
        }
        asm volatile("s_waitcnt lgkmcnt(0)" ::: "memory");
        __builtin_amdgcn_s_barrier();
        __builtin_amdgcn_sched_barrier(0);
    }

#pragma unroll
    for (int r = 0; r < 4; ++r) {
        int grow = brow + w * 16 + lg * 4 + r;
        if (grow >= N) continue;
        float d = dis[grow];
#pragma unroll
        for (int cb = 0; cb < 3; ++cb) {
            int col = cb * 16 + lr;
            if (col < 40) outp[(size_t)grow * 40 + col] = f2bf(d * acc[cb][r]);
        }
    }
}

// ---------------------------------------------------------------------------
// Column-half aggregation: each launch handles 64 of the 128 columns
// (= exactly one 128B cache line per gathered row), so the per-pass working
// set is 6.4 MB vs 4 MB L2/XCD. Two sequential launches cover both halves.
// Wave: 4 sub-groups x 16 lanes; sub-group gathers one edge's 128B line.
// All __shfl wave-uniform (R8 lesson).
template <int HALF>
__global__ __launch_bounds__(256) void agg128h_kernel(
    const unsigned short* __restrict__ hwb,
    const int* __restrict__ row_ptr, const int* __restrict__ csr,
    const float* __restrict__ dis, const float* __restrict__ bias,
    float* __restrict__ outp, unsigned short* __restrict__ hbout, int N)
{
    int wid = threadIdx.x >> 6, lane = threadIdx.x & 63;
    int node = blockIdx.x * 4 + wid;
    if (node >= N) return;
    const int sub = lane >> 4, u = lane & 15;
    const uint2* hw2 = (const uint2*)hwb;      // 32 uint2 per 128-col row
    const int soff = HALF * 16 + u;            // uint2 index within row
    float a[4] = {0.f, 0.f, 0.f, 0.f};
    float b4[4] = {0.f, 0.f, 0.f, 0.f};
    if (sub == 0) addbf4(a, hw2[(size_t)node * 32 + soff]);   // self loop
    int beg = row_ptr[node], end = row_ptr[node + 1];
    for (int base = beg; base < end; base += 64) {
        int idx = base + lane;
        int j = (idx < end) ? csr[idx] : 0;
        int cnt = end - base; if (cnt > 64) cnt = 64;
        int fullq = cnt >> 2;
        int t = 0;
        for (; t + 2 <= fullq; t += 2) {
            int ja = __shfl(j, 4 * t + sub);
            int jb = __shfl(j, 4 * t + 4 + sub);
            uint2 va = hw2[(size_t)ja * 32 + soff];
            uint2 vb = hw2[(size_t)jb * 32 + soff];
            addbf4(a, va); addbf4(b4, vb);
        }
        for (; t < fullq; ++t) {
            int ja = __shfl(j, 4 * t + sub);
            uint2 va = hw2[(size_t)ja * 32 + soff];
            addbf4(a, va);
        }
        int rem = cnt & 3;
        if (rem) {   // wave-uniform shfl; only sub<rem consume
            int srcl = (cnt & ~3) + ((sub < rem) ? sub : 0);
            int ja = __shfl(j, srcl);
            if (sub < rem) {
                uint2 va = hw2[(size_t)ja * 32 + soff];
                addbf4(a, va);
            }
        }
    }
#pragma unroll
    for (int c = 0; c < 4; ++c) {
        a[c] += b4[c];
        a[c] += __shfl_xor(a[c], 16);
        a[c] += __shfl_xor(a[c], 32);
    }
    if (sub == 0) {
        float d = dis[node];
        int col0 = HALF * 64 + u * 4;
        float4 bv = *(const float4*)(bias + col0);
        float4 o;
        o.x = fmaxf(fmaf(d, a[0], bv.x), 0.f);
        o.y = fmaxf(fmaf(d, a[1], bv.y), 0.f);
        o.z = fmaxf(fmaf(d, a[2], bv.z), 0.f);
        o.w = fmaxf(fmaf(d, a[3], bv.w), 0.f);
        *(float4*)(outp + (size_t)node * 128 + col0) = o;
        uint2 pk;
        pk.x = (unsigned)f2bf(o.x) | ((unsigned)f2bf(o.y) << 16);
        pk.y = (unsigned)f2bf(o.z) | ((unsigned)f2bf(o.w) << 16);
        *(uint2*)(hbout + (size_t)node * 128 + col0) = pk;
    }
}

// 40-wide aggregation over bf16 rows (80B each), dual half-wave streams.
__global__ __launch_bounds__(256) void agg40b_kernel(
    const unsigned short* __restrict__ hwb,
    const int* __restrict__ row_ptr, const int* __restrict__ csr,
    const float* __restrict__ dis, const float* __restrict__ bias,
    float* __restrict__ outp, int N)
{
    int wid = threadIdx.x >> 6, lane = threadIdx.x & 63;
    int node = blockIdx.x * 4 + wid;
    if (node >= N) return;
    const int half = lane >> 5, q = lane & 31;
    const bool act = q < 20;
    const unsigned* hw20 = (const unsigned*)hwb;   // 20 uints per 40-col row
    float a0 = 0.f, a1 = 0.f, b0 = 0.f, b1 = 0.f;
    if (half == 0 && act) {
        unsigned v = hw20[(size_t)node * 20 + q];
        a0 += bf2f(v & 0xffffu); a1 += bf2f(v >> 16);
    }
    int beg = row_ptr[node], end = row_ptr[node + 1];
    for (int base = beg; base < end; base += 64) {
        int idx = base + lane;
        int j = (idx < end) ? csr[idx] : 0;
        int cnt = end - base; if (cnt > 64) cnt = 64;
        int fullp = cnt >> 1;
        int t = 0;
        for (; t + 4 <= fullp; t += 4) {
            int ja = __shfl(j, 2 * t     + half);
            int jb = __shfl(j, 2 * t + 2 + half);
            int jc = __shfl(j, 2 * t + 4 + half);
            int jd = __shfl(j, 2 * t + 6 + half);
            if (act) {
                unsigned va = hw20[(size_t)ja * 20 + q];
                unsigned vb = hw20[(size_t)jb * 20 + q];
                unsigned vc = hw20[(size_t)jc * 20 + q];
                unsigned vd = hw20[(size_t)jd * 20 + q];
                a0 += bf2f(va & 0xffffu); a1 += bf2f(va >> 16);
                b0 += bf2f(vb & 0xffffu); b1 += bf2f(vb >> 16);
                a0 += bf2f(vc & 0xffffu); a1 += bf2f(vc >> 16);
                b0 += bf2f(vd & 0xffffu); b1 += bf2f(vd >> 16);
            }
        }
        for (; t < fullp; ++t) {
            int ja = __shfl(j, 2 * t + half);
            if (act) {
                unsigned va = hw20[(size_t)ja * 20 + q];
                a0 += bf2f(va & 0xffffu); a1 += bf2f(va >> 16);
            }
        }
        if (cnt & 1) {
            int ja = __shfl(j, cnt - 1);
            if (half == 0 && act) {
                unsigned va = hw20[(size_t)ja * 20 + q];
                a0 += bf2f(va & 0xffffu); a1 += bf2f(va >> 16);
            }
        }
    }
    a0 += b0; a1 += b1;
    a0 += __shfl_xor(a0, 32);
    a1 += __shfl_xor(a1, 32);
    if (half == 0 && act) {
        float d = dis[node];
        float2 o;
        o.x = fmaf(d, a0, bias[2 * q]);
        o.y = fmaf(d, a1, bias[2 * q + 1]);
        *(float2*)(outp + (size_t)node * 40 + 2 * q) = o;
    }
}

// ---------------------------------------------------------------------------
extern "C" void kernel_launch(void* const* d_in, const int* in_sizes, int n_in,
                              void* d_out, int out_size, void* d_ws, size_t ws_size,
                              hipStream_t stream) {
    const int N = in_sizes[0] / 100;
    const int E = in_sizes[1] / 2;

    const float* x   = (const float*)d_in[0];
    const void*  ei  = d_in[1];
    const float* W1  = (const float*)d_in[4];
    const float* b1  = (const float*)d_in[5];
    const float* W2  = (const float*)d_in[6];
    const float* b2  = (const float*)d_in[7];
    const float* Wm  = (const float*)d_in[8];
    const float* bm  = (const float*)d_in[9];
    const float* Wo  = (const float*)d_in[10];
    const float* bo  = (const float*)d_in[11];
    const float* bn1g = (const float*)d_in[12];
    const float* bn1b = (const float*)d_in[13];
    const float* bn1m = (const float*)d_in[14];
    const float* bn1v = (const float*)d_in[15];
    const float* bn2g = (const float*)d_in[16];
    const float* bn2b = (const float*)d_in[17];
    const float* bn2m = (const float*)d_in[18];
    const float* bn2v = (const float*)d_in[19];
    const float* bnmg = (const float*)d_in[20];
    const float* bnmb = (const float*)d_in[21];
    const float* bnmm = (const float*)d_in[22];
    const float* bnmv = (const float*)d_in[23];
    const float* bnog = (const float*)d_in[24];
    const float* bnob = (const float*)d_in[25];
    const float* bnom = (const float*)d_in[26];
    const float* bnov = (const float*)d_in[27];

    char* wsb = (char*)d_ws;
    size_t off = 0;
    auto alloc = [&](size_t elems) -> void* { void* p = wsb + off; off += elems * 4; return p; };
    int*   deg     = (int*)alloc(N);
    int*   cursor  = (int*)alloc(N);
    int*   row_ptr = (int*)alloc((size_t)N + 1);
    int*   bsum    = (int*)alloc(64);
    int*   flag    = (int*)alloc(1);
    off = (off + 15) & ~(size_t)15;
    float* dis  = (float*)alloc(N);
    int*   csr  = (int*)alloc(E);
    off = (off + 15) & ~(size_t)15;
    unsigned short* hwb = (unsigned short*)alloc((size_t)N * 64);   // N x 128 bf16
    unsigned short* hbA = (unsigned short*)alloc((size_t)N * 64);
    unsigned short* hbB = (unsigned short*)alloc((size_t)N * 64);
    unsigned short* hbC = (unsigned short*)alloc((size_t)N * 64);
    unsigned short* BhiA = (unsigned short*)alloc(63488);
    unsigned short* BloA = (unsigned short*)alloc(63488);
    float* cvecA = (float*)alloc(128 * 5);
    (void)ws_size; (void)n_in; (void)out_size;

    float* outF = (float*)d_out;
    float* h1 = outF + (size_t)N * 40;
    float* h2 = h1 + (size_t)N * 128;
    float* h3 = h2 + (size_t)N * 128;
    float* h4 = h3 + (size_t)N * 128;

    dim3 b256(256);

    // ---- fold all 5 layers' weights (1 launch)
    LayerPs P;
    P.l[0] = {W1, bn1g, bn1b, bn1m, bn1v, 100, 128, 8, 0};
    P.l[1] = {W2, bn2g, bn2b, bn2m, bn2v, 228, 128, 8, 16384};
    P.l[2] = {Wm, bnmg, bnmb, bnmm, bnmv, 256, 128, 8, 49152};
    P.l[3] = {Wm + 256 * 128, bnmg + 256, bnmb + 256, bnmm + 256, bnmv + 256, 256, 128, 8, 81920};
    P.l[4] = {Wo, bnog, bnob, bnom, bnov, 256, 40, 3, 114688};
    fold_all<<<dim3(160, 5), b256, 0, stream>>>(P, BhiA, BloA, cvecA);

    // ---- graph build
    build0_kernel<<<dim3((N + 255) / 256), b256, 0, stream>>>((const int*)ei, flag, deg, cursor, N);
    count_kernel<<<dim3((E + 255) / 256), b256, 0, stream>>>(ei, E, deg, flag);
    int nb = (N + 1023) / 1024;
    scanA_kernel<<<dim3(nb), dim3(1024), 0, stream>>>(deg, row_ptr, bsum, dis, N);
    scanB_kernel<<<1, 64, 0, stream>>>(bsum, nb);
    scanC_kernel<<<dim3(nb), dim3(1024), 0, stream>>>(row_ptr, bsum, N);
    fill_kernel<<<dim3((E + 255) / 256), b256, 0, stream>>>(ei, E, row_ptr, cursor, csr, flag);

    int gemm_grid = (N + 63) / 64;
    int agg_grid  = (N + 3) / 4;

    auto agg128 = [&](const float* lb, float* dst, unsigned short* hbout) {
        agg128h_kernel<0><<<dim3(agg_grid), b256, 0, stream>>>(
            hwb, row_ptr, csr, dis, lb, dst, hbout, N);
        agg128h_kernel<1><<<dim3(agg_grid), b256, 0, stream>>>(
            hwb, row_ptr, csr, dis, lb, dst, hbout, N);
    };

    // L1: bn1 + GCN(W1) + relu -> h1   (x fp32 input)
    gemm_mix2_kernel<false, false><<<dim3(gemm_grid), b256, 0, stream>>>(
        x, 100, 100, nullptr, 0, BhiA + P.l[0].boff, BloA + P.l[0].boff,
        cvecA, dis, hwb, 100, 0, N);
    agg128(b1, h1, hbA);

    // L2: concat(h1 bf16, x fp32) -> h2
    gemm_mix2_kernel<true, false><<<dim3(gemm_grid), b256, 0, stream>>>(
        hbA, 128, 128, x, 100, BhiA + P.l[1].boff, BloA + P.l[1].boff,
        cvecA + 128, dis, hwb, 228, 4, N);
    agg128(b2, h2, hbB);

    // L3: concat(h2, h1) all-bf16 -> h3
    gemm_bf2_kernel<<<dim3(gemm_grid), b256, 0, stream>>>(
        hbB, 128, 128, hbA, 128, BhiA + P.l[2].boff, BloA + P.l[2].boff,
        cvecA + 256, dis, hwb, 256, N);
    agg128(bm, h3, hbC);

    // L4: concat(h3, h2) all-bf16 -> h4 (h4 copy reuses slot A; h1 dead)
    gemm_bf2_kernel<<<dim3(gemm_grid), b256, 0, stream>>>(
        hbC, 128, 128, hbB, 128, BhiA + P.l[3].boff, BloA + P.l[3].boff,
        cvecA + 384, dis, hwb, 256, N);
    agg128(bm + 128, h4, hbA);

    // L5: concat(h4, h3) all-bf16 -> out (40-wide, no relu)
    gemm_bf40_kernel<<<dim3(gemm_grid), b256, 0, stream>>>(
        hbA, 128, 128, hbC, 128, BhiA + P.l[4].boff, BloA + P.l[4].boff,
        cvecA + 512, dis, hwb, 256, N);
    agg40b_kernel<<<dim3(agg_grid), b256, 0, stream>>>(hwb, row_ptr, csr, dis, bo, outF, N);
}

// Round 14
// 377.772 us; speedup vs baseline: 1.2523x; 1.2523x over previous
//
#include <hip/hip_runtime.h>
#include <hip/hip_bf16.h>
#include <cstdint>
#include <cstddef>

#define BN_EPS 1e-5f
typedef long long ll;
using bf16x8 = __attribute__((ext_vector_type(8))) short;
using f32x4  = __attribute__((ext_vector_type(4))) float;

__device__ __forceinline__ unsigned short f2bf(float f) {
    union { float f; unsigned u; } c; c.f = f;
    unsigned u = c.u;
    u += 0x7fff + ((u >> 16) & 1);   // round-to-nearest-even
    return (unsigned short)(u >> 16);
}
__device__ __forceinline__ float bf2f(unsigned h) {
    union { unsigned u; float f; } c; c.u = h << 16;
    return c.f;
}
__device__ __forceinline__ void addbf8(float* a, uint4 v) {
    a[0] += bf2f(v.x & 0xffffu); a[1] += bf2f(v.x >> 16);
    a[2] += bf2f(v.y & 0xffffu); a[3] += bf2f(v.y >> 16);
    a[4] += bf2f(v.z & 0xffffu); a[5] += bf2f(v.z >> 16);
    a[6] += bf2f(v.w & 0xffffu); a[7] += bf2f(v.w >> 16);
}
__device__ __forceinline__ float4 bf4_to_f4(uint2 v) {
    return make_float4(bf2f(v.x & 0xffffu), bf2f(v.x >> 16),
                       bf2f(v.y & 0xffffu), bf2f(v.y >> 16));
}
// Async global->LDS, 16B per lane. LDS base must be wave-uniform; HW writes
// lane i's 16B at base + i*16.
__device__ __forceinline__ void gload_lds16(const void* g, void* lds) {
    __builtin_amdgcn_global_load_lds(
        (const __attribute__((address_space(1))) unsigned int*)g,
        (__attribute__((address_space(3))) unsigned int*)lds, 16, 0, 0);
}

// ---------------------------------------------------------------------------
// detect (block 0) + init, merged.
__global__ void build0_kernel(const int* ei32, int* flag, int* deg, int* cursor, int N) {
    int i = blockIdx.x * 256 + threadIdx.x;
    if (i < N) { deg[i] = 1; cursor[i] = 0; }   // deg starts at 1 (self loop)
    if (blockIdx.x == 0) {
        __shared__ int any;
        if (threadIdx.x == 0) any = 0;
        __syncthreads();
        for (int t = threadIdx.x; t < 2048; t += 256)
            if (ei32[2 * t + 1] != 0) any = 1;
        __syncthreads();
        if (threadIdx.x == 0) *flag = (any == 0) ? 1 : 0;
    }
}

__global__ void count_kernel(const void* ei, int E, int* deg, const int* flag) {
    int e = blockIdx.x * 256 + threadIdx.x;
    if (e >= E) return;
    int d = (*flag) ? (int)((const ll*)ei)[(size_t)E + e]
                    : ((const int*)ei)[(size_t)E + e];
    atomicAdd(&deg[d], 1);
}

// Block-level inclusive scan of (deg[i]-1); bsum[b] = block total; also dis.
__global__ __launch_bounds__(1024) void scanA_kernel(const int* deg, int* row_ptr,
                                                     int* bsum, float* dis, int N) {
    __shared__ int wsum[16];
    int i = blockIdx.x * 1024 + threadIdx.x;
    int lane = threadIdx.x & 63, wid = threadIdx.x >> 6;
    int dv = (i < N) ? deg[i] : 1;
    if (i < N) dis[i] = rsqrtf((float)dv);
    int v = (i < N) ? (dv - 1) : 0;
    int s = v;
#pragma unroll
    for (int o = 1; o < 64; o <<= 1) { int t = __shfl_up(s, o); if (lane >= o) s += t; }
    if (lane == 63) wsum[wid] = s;
    __syncthreads();
    if (threadIdx.x < 16) {
        int w = wsum[threadIdx.x];
        int ws_ = w;
#pragma unroll
        for (int o = 1; o < 16; o <<= 1) { int t = __shfl_up(ws_, o); if ((int)threadIdx.x >= o) ws_ += t; }
        wsum[threadIdx.x] = ws_ - w;  // exclusive wave offset
    }
    __syncthreads();
    s += wsum[wid];
    if (i < N) row_ptr[i + 1] = s;
    if (threadIdx.x == 1023) bsum[blockIdx.x] = s;
}

__global__ void scanB_kernel(int* bsum, int nb) {
    int lane = threadIdx.x;
    int v = (lane < nb) ? bsum[lane] : 0;
    int s = v;
#pragma unroll
    for (int o = 1; o < 64; o <<= 1) { int t = __shfl_up(s, o); if (lane >= o) s += t; }
    if (lane < nb) bsum[lane] = s - v;  // exclusive block offsets
}

__global__ __launch_bounds__(1024) void scanC_kernel(int* row_ptr, const int* bsum, int N) {
    int i = blockIdx.x * 1024 + threadIdx.x;
    if (i < N) row_ptr[i + 1] += bsum[blockIdx.x];
    if (i == 0) row_ptr[0] = 0;
}

__global__ void fill_kernel(const void* ei, int E, const int* row_ptr,
                            int* cursor, int* csr, const int* flag) {
    int e = blockIdx.x * 256 + threadIdx.x;
    if (e >= E) return;
    int s, d;
    if (*flag) { const ll* p = (const ll*)ei; s = (int)p[e]; d = (int)p[(size_t)E + e]; }
    else       { const int* p = (const int*)ei; s = p[e]; d = p[(size_t)E + e]; }
    int pos = atomicAdd(&cursor[d], 1);
    csr[row_ptr[d] + pos] = s;
}

// ---------------------------------------------------------------------------
struct LayerP {
    const float *W, *g, *b, *m, *v;
    int K, Dout, ncb, boff;
};
struct LayerPs { LayerP l[5]; };

// Merged fold: blockIdx.x<128 -> B-fragment packing; >=128 -> cvec.
// B fragment: lane l, slot i holds W'[kc*32 + 8*(l>>4) + i][cb*16 + (l&15)].
__global__ __launch_bounds__(256) void fold_all(LayerPs P,
                                                unsigned short* __restrict__ Bhi,
                                                unsigned short* __restrict__ Blo,
                                                float* __restrict__ cvecA) {
    const LayerP& L = P.l[blockIdx.y];
    if (blockIdx.x < 128) {
        int nkc = (L.K + 63) >> 6 << 1;   // chunks padded to BK=64 pairs
        int total = nkc * L.ncb * 512;
        int idx = blockIdx.x * 256 + threadIdx.x;
        if (idx >= total) return;
        int i = idx & 7;
        int lane = (idx >> 3) & 63;
        int cb = (idx >> 9) % L.ncb;
        int kc = (idx >> 9) / L.ncb;
        int k = kc * 32 + (lane >> 4) * 8 + i;
        int col = cb * 16 + (lane & 15);
        float val = 0.f;
        if (k < L.K && col < L.Dout) {
            float s = L.g[k] * rsqrtf(L.v[k] + BN_EPS);
            val = L.W[k * L.Dout + col] * s;
        }
        unsigned short h = f2bf(val);
        Bhi[L.boff + idx] = h;
        Blo[L.boff + idx] = f2bf(val - bf2f(h));
    } else {
        int wid = threadIdx.x >> 6, lane = threadIdx.x & 63;
        int col = (blockIdx.x - 128) * 4 + wid;
        float acc = 0.f;
        if (col < L.Dout) {
            for (int k = lane; k < L.K; k += 64) {
                float s = L.g[k] * rsqrtf(L.v[k] + BN_EPS);
                acc += (L.b[k] - L.m[k] * s) * L.W[k * L.Dout + col];
            }
        }
#pragma unroll
        for (int o = 32; o >= 1; o >>= 1) acc += __shfl_xor(acc, o);
        if (lane == 0 && col < 128) cvecA[128 * blockIdx.y + col] = (col < L.Dout) ? acc : 0.f;
    }
}

// ---------------------------------------------------------------------------
// Dout=128 all-bf16 GEMM, 2-phase double-buffered staging (counted vmcnt,
// raw s_barrier — stage k+1's loads stay in flight across the barrier).
// Wave w owns col-blocks {2w,2w+1} over all 64 rows.
__global__ __launch_bounds__(256, 4) void gemm_bf2_kernel(
    const unsigned short* __restrict__ X1, int K1, int ld1,
    const unsigned short* __restrict__ X2, int ld2,
    const unsigned short* __restrict__ Bhi, const unsigned short* __restrict__ Blo,
    const float* __restrict__ cvec, const float* __restrict__ dis,
    unsigned short* __restrict__ outp, int K, int N)
{
    __shared__ unsigned short Xs[2][64 * 64];   // 2 x 8KB, linear [row][slot*8]
    const int tid = threadIdx.x;
    const int w = tid >> 6, lane = tid & 63;
    const int lr = lane & 15, lg = lane >> 4;
    const int brow = blockIdx.x * 64;
    const int nkt = (K + 63) >> 6;
    const int cb0 = 2 * w;

    int s_r[2], s_sl[2];
#pragma unroll
    for (int p = 0; p < 2; ++p) {
        int idx = p * 256 + tid;
        s_r[p] = idx >> 3;
        s_sl[p] = idx & 7;
    }

    auto STAGE = [&](int kt, int b) {
        const int k0 = kt * 64;
        const unsigned short* T = (k0 < K1) ? X1 : X2;
        const int ldT = (k0 < K1) ? ld1 : ld2;
        const int kb = (k0 < K1) ? k0 : (k0 - K1);
#pragma unroll
        for (int p = 0; p < 2; ++p) {
            int grow = brow + s_r[p]; if (grow >= N) grow = N - 1;
            int ksl = s_sl[p] ^ (s_r[p] & 7);    // source slot pre-swizzle
            gload_lds16(T + (size_t)grow * ldT + kb + ksl * 8,
                        (char*)Xs[b] + (size_t)(p * 256 + w * 64) * 16);
        }
    };

    f32x4 acc[4][2];
#pragma unroll
    for (int c = 0; c < 2; ++c) {
        float cv = cvec[(cb0 + c) * 16 + lr];
        f32x4 iv = {cv, cv, cv, cv};
#pragma unroll
        for (int rb = 0; rb < 4; ++rb) acc[rb][c] = iv;
    }

    STAGE(0, 0);
    for (int kt = 0; kt < nkt; ++kt) {
        const int cur = kt & 1;
        if (kt + 1 < nkt) STAGE(kt + 1, cur ^ 1);
        __builtin_amdgcn_sched_barrier(0);
        if (kt + 1 < nkt) asm volatile("s_waitcnt vmcnt(2)" ::: "memory");
        else              asm volatile("s_waitcnt vmcnt(0)" ::: "memory");
        __builtin_amdgcn_s_barrier();
        __builtin_amdgcn_sched_barrier(0);

#pragma unroll
        for (int ks = 0; ks < 2; ++ks) {
            const int kcg = kt * 2 + ks;
            bf16x8 a[4];
#pragma unroll
            for (int rb = 0; rb < 4; ++rb) {
                int r = rb * 16 + lr;
                a[rb] = *(const bf16x8*)((const char*)Xs[cur] + r * 128 +
                                         ((ks * 64 + lg * 16) ^ ((r & 7) << 4)));
            }
            const bf16x8* bh = (const bf16x8*)Bhi + (size_t)kcg * 8 * 64;
            const bf16x8* bl = (const bf16x8*)Blo + (size_t)kcg * 8 * 64;
#pragma unroll
            for (int c = 0; c < 2; ++c) {
                bf16x8 bhf = bh[(cb0 + c) * 64 + lane];
                bf16x8 blf = bl[(cb0 + c) * 64 + lane];
#pragma unroll
                for (int rb = 0; rb < 4; ++rb) {
                    acc[rb][c] = __builtin_amdgcn_mfma_f32_16x16x32_bf16(a[rb], bhf, acc[rb][c], 0, 0, 0);
                    acc[rb][c] = __builtin_amdgcn_mfma_f32_16x16x32_bf16(a[rb], blf, acc[rb][c], 0, 0, 0);
                }
            }
        }
        asm volatile("s_waitcnt lgkmcnt(0)" ::: "memory");
        __builtin_amdgcn_s_barrier();
        __builtin_amdgcn_sched_barrier(0);
    }

    // D lane map: row = (lane>>4)*4 + reg, col = lane&15
#pragma unroll
    for (int rb = 0; rb < 4; ++rb) {
#pragma unroll
        for (int r = 0; r < 4; ++r) {
            int grow = brow + rb * 16 + lg * 4 + r;
            if (grow >= N) continue;
            float d = dis[grow];
#pragma unroll
            for (int c = 0; c < 2; ++c)
                outp[(size_t)grow * 128 + (cb0 + c) * 16 + lr] = f2bf(d * acc[rb][c][r]);
        }
    }
}

// Dout=128 mixed GEMM: stage hi/lo bf16 planes in LDS (split done once at
// staging), inner loop = bf2 + optional lo-MFMA. B1/B2: source is bf16.
template <bool B1, bool B2>
__global__ __launch_bounds__(256, 3) void gemm_mix2_kernel(
    const void* __restrict__ X1, int K1, int ld1,
    const void* __restrict__ X2, int ld2,
    const unsigned short* __restrict__ Bhi, const unsigned short* __restrict__ Blo,
    const float* __restrict__ cvec, const float* __restrict__ dis,
    unsigned short* __restrict__ outp, int K, int kc_lo, int N)
{
    __shared__ unsigned short Xhi[64 * 64];
    __shared__ unsigned short Xlo[64 * 64];
    const int tid = threadIdx.x;
    const int w = tid >> 6, lane = tid & 63;
    const int lr = lane & 15, lg = lane >> 4;
    const int brow = blockIdx.x * 64;
    const int nkt = (K + 63) >> 6;
    const int cb0 = 2 * w;

    f32x4 acc[4][2];
#pragma unroll
    for (int c = 0; c < 2; ++c) {
        float cv = cvec[(cb0 + c) * 16 + lr];
        f32x4 iv = {cv, cv, cv, cv};
#pragma unroll
        for (int rb = 0; rb < 4; ++rb) acc[rb][c] = iv;
    }

    for (int kt = 0; kt < nkt; ++kt) {
        const int k0 = kt * 64;
        const bool kt_lo = (kt * 2 + 1) >= kc_lo;   // this kt has fp32 source
#pragma unroll
        for (int p = 0; p < 4; ++p) {
            int fidx = (p * 256 + tid) * 4;
            int r = fidx >> 6;
            int c = fidx & 63;
            int grow = brow + r;
            int k = k0 + c;
            float4 val = make_float4(0.f, 0.f, 0.f, 0.f);
            if (grow < N) {
                if (k < K1) {
                    if (B1) val = bf4_to_f4(*(const uint2*)((const unsigned short*)X1 + (size_t)grow * ld1 + k));
                    else    val = *(const float4*)((const float*)X1 + (size_t)grow * ld1 + k);
                } else if (k < K) {
                    int kk = k - K1;
                    if (B2) val = bf4_to_f4(*(const uint2*)((const unsigned short*)X2 + (size_t)grow * ld2 + kk));
                    else    val = *(const float4*)((const float*)X2 + (size_t)grow * ld2 + kk);
                }
            }
            unsigned short h0 = f2bf(val.x), h1 = f2bf(val.y),
                           h2 = f2bf(val.z), h3 = f2bf(val.w);
            int b8 = c * 2;
            int addr = r * 128 + (((b8 & 0x70) ^ ((r & 7) << 4)) | (b8 & 8));
            *(uint2*)((char*)Xhi + addr) =
                make_uint2((unsigned)h0 | ((unsigned)h1 << 16),
                           (unsigned)h2 | ((unsigned)h3 << 16));
            if (kt_lo) {
                unsigned short l0 = f2bf(val.x - bf2f(h0)), l1 = f2bf(val.y - bf2f(h1)),
                               l2 = f2bf(val.z - bf2f(h2)), l3 = f2bf(val.w - bf2f(h3));
                *(uint2*)((char*)Xlo + addr) =
                    make_uint2((unsigned)l0 | ((unsigned)l1 << 16),
                               (unsigned)l2 | ((unsigned)l3 << 16));
            }
        }
        __syncthreads();

#pragma unroll
        for (int ks = 0; ks < 2; ++ks) {
            const int kcg = kt * 2 + ks;
            const bool need_lo = (kcg >= kc_lo);
            bf16x8 ah[4], al[4];
#pragma unroll
            for (int rb = 0; rb < 4; ++rb) {
                int r = rb * 16 + lr;
                int off = ((ks * 64 + lg * 16) ^ ((r & 7) << 4));
                ah[rb] = *(const bf16x8*)((const char*)Xhi + r * 128 + off);
                if (need_lo) al[rb] = *(const bf16x8*)((const char*)Xlo + r * 128 + off);
            }
            const bf16x8* bh = (const bf16x8*)Bhi + (size_t)kcg * 8 * 64;
            const bf16x8* bl = (const bf16x8*)Blo + (size_t)kcg * 8 * 64;
#pragma unroll
            for (int c = 0; c < 2; ++c) {
                bf16x8 bhf = bh[(cb0 + c) * 64 + lane];
                bf16x8 blf = bl[(cb0 + c) * 64 + lane];
#pragma unroll
                for (int rb = 0; rb < 4; ++rb) {
                    acc[rb][c] = __builtin_amdgcn_mfma_f32_16x16x32_bf16(ah[rb], bhf, acc[rb][c], 0, 0, 0);
                    acc[rb][c] = __builtin_amdgcn_mfma_f32_16x16x32_bf16(ah[rb], blf, acc[rb][c], 0, 0, 0);
                    if (need_lo)
                        acc[rb][c] = __builtin_amdgcn_mfma_f32_16x16x32_bf16(al[rb], bhf, acc[rb][c], 0, 0, 0);
                }
            }
        }
        __syncthreads();
    }

#pragma unroll
    for (int rb = 0; rb < 4; ++rb) {
#pragma unroll
        for (int r = 0; r < 4; ++r) {
            int grow = brow + rb * 16 + lg * 4 + r;
            if (grow >= N) continue;
            float d = dis[grow];
#pragma unroll
            for (int c = 0; c < 2; ++c)
                outp[(size_t)grow * 128 + (cb0 + c) * 16 + lr] = f2bf(d * acc[rb][c][r]);
        }
    }
}

// Dout=40 all-bf16 GEMM (L5): wave per 16 rows, all 3 col-blocks,
// same 2-phase double-buffered staging as bf2.
__global__ __launch_bounds__(256, 4) void gemm_bf40_kernel(
    const unsigned short* __restrict__ X1, int K1, int ld1,
    const unsigned short* __restrict__ X2, int ld2,
    const unsigned short* __restrict__ Bhi, const unsigned short* __restrict__ Blo,
    const float* __restrict__ cvec, const float* __restrict__ dis,
    unsigned short* __restrict__ outp, int K, int N)
{
    __shared__ unsigned short Xs[2][64 * 64];
    const int tid = threadIdx.x;
    const int w = tid >> 6, lane = tid & 63;
    const int lr = lane & 15, lg = lane >> 4;
    const int brow = blockIdx.x * 64;
    const int nkt = (K + 63) >> 6;

    int s_r[2], s_sl[2];
#pragma unroll
    for (int p = 0; p < 2; ++p) {
        int idx = p * 256 + tid;
        s_r[p] = idx >> 3;
        s_sl[p] = idx & 7;
    }
    auto STAGE = [&](int kt, int b) {
        const int k0 = kt * 64;
        const unsigned short* T = (k0 < K1) ? X1 : X2;
        const int ldT = (k0 < K1) ? ld1 : ld2;
        const int kb = (k0 < K1) ? k0 : (k0 - K1);
#pragma unroll
        for (int p = 0; p < 2; ++p) {
            int grow = brow + s_r[p]; if (grow >= N) grow = N - 1;
            int ksl = s_sl[p] ^ (s_r[p] & 7);
            gload_lds16(T + (size_t)grow * ldT + kb + ksl * 8,
                        (char*)Xs[b] + (size_t)(p * 256 + w * 64) * 16);
        }
    };

    f32x4 acc[3];
#pragma unroll
    for (int cb = 0; cb < 3; ++cb) {
        float cv = cvec[cb * 16 + lr];
        f32x4 iv = {cv, cv, cv, cv};
        acc[cb] = iv;
    }

    STAGE(0, 0);
    for (int kt = 0; kt < nkt; ++kt) {
        const int cur = kt & 1;
        if (kt + 1 < nkt) STAGE(kt + 1, cur ^ 1);
        __builtin_amdgcn_sched_barrier(0);
        if (kt + 1 < nkt) asm volatile("s_waitcnt vmcnt(2)" ::: "memory");
        else              asm volatile("s_waitcnt vmcnt(0)" ::: "memory");
        __builtin_amdgcn_s_barrier();
        __builtin_amdgcn_sched_barrier(0);

        const int r = w * 16 + lr;
        const char* base = (const char*)Xs[cur] + r * 128;
        const int swz = (r & 7) << 4;
        bf16x8 a0 = *(const bf16x8*)(base + ((lg * 16) ^ swz));
        bf16x8 a1 = *(const bf16x8*)(base + ((64 + lg * 16) ^ swz));
#pragma unroll
        for (int ks = 0; ks < 2; ++ks) {
            const int kcg = kt * 2 + ks;
            const bf16x8 af = ks ? a1 : a0;
            const bf16x8* bh = (const bf16x8*)Bhi + (size_t)kcg * 3 * 64;
            const bf16x8* bl = (const bf16x8*)Blo + (size_t)kcg * 3 * 64;
#pragma unroll
            for (int cb = 0; cb < 3; ++cb) {
                bf16x8 bhf = bh[cb * 64 + lane];
                bf16x8 blf = bl[cb * 64 + lane];
                acc[cb] = __builtin_amdgcn_mfma_f32_16x16x32_bf16(af, bhf, acc[cb], 0, 0, 0);
                acc[cb] = __builtin_amdgcn_mfma_f32_16x16x32_bf16(af, blf, acc[cb], 0, 0, 0);
            }
        }
        asm volatile("s_waitcnt lgkmcnt(0)" ::: "memory");
        __builtin_amdgcn_s_barrier();
        __builtin_amdgcn_sched_barrier(0);
    }

#pragma unroll
    for (int r = 0; r < 4; ++r) {
        int grow = brow + w * 16 + lg * 4 + r;
        if (grow >= N) continue;
        float d = dis[grow];
#pragma unroll
        for (int cb = 0; cb < 3; ++cb) {
            int col = cb * 16 + lr;
            if (col < 40) outp[(size_t)grow * 40 + col] = f2bf(d * acc[cb][r]);
        }
    }
}

// ---------------------------------------------------------------------------
// 128-wide aggregation over bf16 rows, 16B/lane (uint4), 4 quarter-wave
// streams. Writes fp32 h + bf16 copy. All __shfl wave-uniform (R8 lesson).
template <bool RELU>
__global__ __launch_bounds__(256) void agg128b_kernel(
    const unsigned short* __restrict__ hwb,
    const int* __restrict__ row_ptr, const int* __restrict__ csr,
    const float* __restrict__ dis, const float* __restrict__ bias,
    float* __restrict__ outp, unsigned short* __restrict__ hbout, int N)
{
    int wid = threadIdx.x >> 6, lane = threadIdx.x & 63;
    int node = blockIdx.x * 4 + wid;
    if (node >= N) return;
    const int sg = lane >> 4, q = lane & 15;
    const uint4* hw4 = (const uint4*)hwb;      // 16 uint4 per 128-col row
    float a[8] = {0.f, 0.f, 0.f, 0.f, 0.f, 0.f, 0.f, 0.f};
    float b8[8] = {0.f, 0.f, 0.f, 0.f, 0.f, 0.f, 0.f, 0.f};
    if (sg == 0) addbf8(a, hw4[(size_t)node * 16 + q]);    // self loop
    int beg = row_ptr[node], end = row_ptr[node + 1];
    for (int base = beg; base < end; base += 64) {
        int idx = base + lane;
        int j = (idx < end) ? csr[idx] : 0;
        int cnt = end - base; if (cnt > 64) cnt = 64;
        int fullq = cnt >> 2;
        int t = 0;
        for (; t + 2 <= fullq; t += 2) {
            int ja = __shfl(j, 4 * t + sg);
            int jb = __shfl(j, 4 * t + 4 + sg);
            uint4 va = hw4[(size_t)ja * 16 + q];
            uint4 vb = hw4[(size_t)jb * 16 + q];
            addbf8(a, va); addbf8(b8, vb);
        }
        for (; t < fullq; ++t) {
            int ja = __shfl(j, 4 * t + sg);
            uint4 va = hw4[(size_t)ja * 16 + q];
            addbf8(a, va);
        }
        int rem = cnt & 3;
        if (rem) {   // wave-uniform: all lanes run the shfl; only sg<rem consume
            int srcl = (cnt & ~3) + ((sg < rem) ? sg : 0);
            int ja = __shfl(j, srcl);
            if (sg < rem) {
                uint4 va = hw4[(size_t)ja * 16 + q];
                addbf8(a, va);
            }
        }
    }
#pragma unroll
    for (int c = 0; c < 8; ++c) {
        a[c] += b8[c];
        a[c] += __shfl_xor(a[c], 16);
        a[c] += __shfl_xor(a[c], 32);
    }
    if (sg == 0) {
        float d = dis[node];
        float4 bv0 = ((const float4*)bias)[q * 2];
        float4 bv1 = ((const float4*)bias)[q * 2 + 1];
        float o[8];
        o[0] = fmaf(d, a[0], bv0.x); o[1] = fmaf(d, a[1], bv0.y);
        o[2] = fmaf(d, a[2], bv0.z); o[3] = fmaf(d, a[3], bv0.w);
        o[4] = fmaf(d, a[4], bv1.x); o[5] = fmaf(d, a[5], bv1.y);
        o[6] = fmaf(d, a[6], bv1.z); o[7] = fmaf(d, a[7], bv1.w);
        if (RELU) {
#pragma unroll
            for (int c = 0; c < 8; ++c) o[c] = fmaxf(o[c], 0.f);
        }
        ((float4*)outp)[(size_t)node * 32 + q * 2]     = make_float4(o[0], o[1], o[2], o[3]);
        ((float4*)outp)[(size_t)node * 32 + q * 2 + 1] = make_float4(o[4], o[5], o[6], o[7]);
        uint4 pk;
        pk.x = (unsigned)f2bf(o[0]) | ((unsigned)f2bf(o[1]) << 16);
        pk.y = (unsigned)f2bf(o[2]) | ((unsigned)f2bf(o[3]) << 16);
        pk.z = (unsigned)f2bf(o[4]) | ((unsigned)f2bf(o[5]) << 16);
        pk.w = (unsigned)f2bf(o[6]) | ((unsigned)f2bf(o[7]) << 16);
        ((uint4*)hbout)[(size_t)node * 16 + q] = pk;
    }
}

// 40-wide aggregation over bf16 rows (80B each), dual half-wave streams.
__global__ __launch_bounds__(256) void agg40b_kernel(
    const unsigned short* __restrict__ hwb,
    const int* __restrict__ row_ptr, const int* __restrict__ csr,
    const float* __restrict__ dis, const float* __restrict__ bias,
    float* __restrict__ outp, int N)
{
    int wid = threadIdx.x >> 6, lane = threadIdx.x & 63;
    int node = blockIdx.x * 4 + wid;
    if (node >= N) return;
    const int half = lane >> 5, q = lane & 31;
    const bool act = q < 20;
    const unsigned* hw20 = (const unsigned*)hwb;   // 20 uints per 40-col row
    float a0 = 0.f, a1 = 0.f, b0 = 0.f, b1 = 0.f;
    if (half == 0 && act) {
        unsigned v = hw20[(size_t)node * 20 + q];
        a0 += bf2f(v & 0xffffu); a1 += bf2f(v >> 16);
    }
    int beg = row_ptr[node], end = row_ptr[node + 1];
    for (int base = beg; base < end; base += 64) {
        int idx = base + lane;
        int j = (idx < end) ? csr[idx] : 0;
        int cnt = end - base; if (cnt > 64) cnt = 64;
        int fullp = cnt >> 1;
        int t = 0;
        for (; t + 4 <= fullp; t += 4) {
            int ja = __shfl(j, 2 * t     + half);
            int jb = __shfl(j, 2 * t + 2 + half);
            int jc = __shfl(j, 2 * t + 4 + half);
            int jd = __shfl(j, 2 * t + 6 + half);
            if (act) {
                unsigned va = hw20[(size_t)ja * 20 + q];
                unsigned vb = hw20[(size_t)jb * 20 + q];
                unsigned vc = hw20[(size_t)jc * 20 + q];
                unsigned vd = hw20[(size_t)jd * 20 + q];
                a0 += bf2f(va & 0xffffu); a1 += bf2f(va >> 16);
                b0 += bf2f(vb & 0xffffu); b1 += bf2f(vb >> 16);
                a0 += bf2f(vc & 0xffffu); a1 += bf2f(vc >> 16);
                b0 += bf2f(vd & 0xffffu); b1 += bf2f(vd >> 16);
            }
        }
        for (; t < fullp; ++t) {
            int ja = __shfl(j, 2 * t + half);
            if (act) {
                unsigned va = hw20[(size_t)ja * 20 + q];
                a0 += bf2f(va & 0xffffu); a1 += bf2f(va >> 16);
            }
        }
        if (cnt & 1) {
            int ja = __shfl(j, cnt - 1);
            if (half == 0 && act) {
                unsigned va = hw20[(size_t)ja * 20 + q];
                a0 += bf2f(va & 0xffffu); a1 += bf2f(va >> 16);
            }
        }
    }
    a0 += b0; a1 += b1;
    a0 += __shfl_xor(a0, 32);
    a1 += __shfl_xor(a1, 32);
    if (half == 0 && act) {
        float d = dis[node];
        float2 o;
        o.x = fmaf(d, a0, bias[2 * q]);
        o.y = fmaf(d, a1, bias[2 * q + 1]);
        *(float2*)(outp + (size_t)node * 40 + 2 * q) = o;
    }
}

// ---------------------------------------------------------------------------
extern "C" void kernel_launch(void* const* d_in, const int* in_sizes, int n_in,
                              void* d_out, int out_size, void* d_ws, size_t ws_size,
                              hipStream_t stream) {
    const int N = in_sizes[0] / 100;
    const int E = in_sizes[1] / 2;

    const float* x   = (const float*)d_in[0];
    const void*  ei  = d_in[1];
    const float* W1  = (const float*)d_in[4];
    const float* b1  = (const float*)d_in[5];
    const float* W2  = (const float*)d_in[6];
    const float* b2  = (const float*)d_in[7];
    const float* Wm  = (const float*)d_in[8];
    const float* bm  = (const float*)d_in[9];
    const float* Wo  = (const float*)d_in[10];
    const float* bo  = (const float*)d_in[11];
    const float* bn1g = (const float*)d_in[12];
    const float* bn1b = (const float*)d_in[13];
    const float* bn1m = (const float*)d_in[14];
    const float* bn1v = (const float*)d_in[15];
    const float* bn2g = (const float*)d_in[16];
    const float* bn2b = (const float*)d_in[17];
    const float* bn2m = (const float*)d_in[18];
    const float* bn2v = (const float*)d_in[19];
    const float* bnmg = (const float*)d_in[20];
    const float* bnmb = (const float*)d_in[21];
    const float* bnmm = (const float*)d_in[22];
    const float* bnmv = (const float*)d_in[23];
    const float* bnog = (const float*)d_in[24];
    const float* bnob = (const float*)d_in[25];
    const float* bnom = (const float*)d_in[26];
    const float* bnov = (const float*)d_in[27];

    char* wsb = (char*)d_ws;
    size_t off = 0;
    auto alloc = [&](size_t elems) -> void* { void* p = wsb + off; off += elems * 4; return p; };
    int*   deg     = (int*)alloc(N);
    int*   cursor  = (int*)alloc(N);
    int*   row_ptr = (int*)alloc((size_t)N + 1);
    int*   bsum    = (int*)alloc(64);
    int*   flag    = (int*)alloc(1);
    off = (off + 15) & ~(size_t)15;
    float* dis  = (float*)alloc(N);
    int*   csr  = (int*)alloc(E);
    off = (off + 15) & ~(size_t)15;
    unsigned short* hwb = (unsigned short*)alloc((size_t)N * 64);   // N x 128 bf16
    unsigned short* hbA = (unsigned short*)alloc((size_t)N * 64);
    unsigned short* hbB = (unsigned short*)alloc((size_t)N * 64);
    unsigned short* hbC = (unsigned short*)alloc((size_t)N * 64);
    unsigned short* BhiA = (unsigned short*)alloc(63488);
    unsigned short* BloA = (unsigned short*)alloc(63488);
    float* cvecA = (float*)alloc(128 * 5);
    (void)ws_size; (void)n_in; (void)out_size;

    float* outF = (float*)d_out;
    float* h1 = outF + (size_t)N * 40;
    float* h2 = h1 + (size_t)N * 128;
    float* h3 = h2 + (size_t)N * 128;
    float* h4 = h3 + (size_t)N * 128;

    dim3 b256(256);

    // ---- fold all 5 layers' weights (1 launch)
    LayerPs P;
    P.l[0] = {W1, bn1g, bn1b, bn1m, bn1v, 100, 128, 8, 0};
    P.l[1] = {W2, bn2g, bn2b, bn2m, bn2v, 228, 128, 8, 16384};
    P.l[2] = {Wm, bnmg, bnmb, bnmm, bnmv, 256, 128, 8, 49152};
    P.l[3] = {Wm + 256 * 128, bnmg + 256, bnmb + 256, bnmm + 256, bnmv + 256, 256, 128, 8, 81920};
    P.l[4] = {Wo, bnog, bnob, bnom, bnov, 256, 40, 3, 114688};
    fold_all<<<dim3(160, 5), b256, 0, stream>>>(P, BhiA, BloA, cvecA);

    // ---- graph build
    build0_kernel<<<dim3((N + 255) / 256), b256, 0, stream>>>((const int*)ei, flag, deg, cursor, N);
    count_kernel<<<dim3((E + 255) / 256), b256, 0, stream>>>(ei, E, deg, flag);
    int nb = (N + 1023) / 1024;
    scanA_kernel<<<dim3(nb), dim3(1024), 0, stream>>>(deg, row_ptr, bsum, dis, N);
    scanB_kernel<<<1, 64, 0, stream>>>(bsum, nb);
    scanC_kernel<<<dim3(nb), dim3(1024), 0, stream>>>(row_ptr, bsum, N);
    fill_kernel<<<dim3((E + 255) / 256), b256, 0, stream>>>(ei, E, row_ptr, cursor, csr, flag);

    int gemm_grid = (N + 63) / 64;
    int agg_grid  = (N + 3) / 4;

    auto agg128 = [&](const float* lb, float* dst, unsigned short* hbout) {
        agg128b_kernel<true><<<dim3(agg_grid), b256, 0, stream>>>(
            hwb, row_ptr, csr, dis, lb, dst, hbout, N);
    };

    // L1: bn1 + GCN(W1) + relu -> h1   (x fp32 input)
    gemm_mix2_kernel<false, false><<<dim3(gemm_grid), b256, 0, stream>>>(
        x, 100, 100, nullptr, 0, BhiA + P.l[0].boff, BloA + P.l[0].boff,
        cvecA, dis, hwb, 100, 0, N);
    agg128(b1, h1, hbA);

    // L2: concat(h1 bf16, x fp32) -> h2
    gemm_mix2_kernel<true, false><<<dim3(gemm_grid), b256, 0, stream>>>(
        hbA, 128, 128, x, 100, BhiA + P.l[1].boff, BloA + P.l[1].boff,
        cvecA + 128, dis, hwb, 228, 4, N);
    agg128(b2, h2, hbB);

    // L3: concat(h2, h1) all-bf16 -> h3
    gemm_bf2_kernel<<<dim3(gemm_grid), b256, 0, stream>>>(
        hbB, 128, 128, hbA, 128, BhiA + P.l[2].boff, BloA + P.l[2].boff,
        cvecA + 256, dis, hwb, 256, N);
    agg128(bm, h3, hbC);

    // L4: concat(h3, h2) all-bf16 -> h4 (h4 copy reuses slot A; h1 dead)
    gemm_bf2_kernel<<<dim3(gemm_grid), b256, 0, stream>>>(
        hbC, 128, 128, hbB, 128, BhiA + P.l[3].boff, BloA + P.l[3].boff,
        cvecA + 384, dis, hwb, 256, N);
    agg128(bm + 128, h4, hbA);

    // L5: concat(h4, h3) all-bf16 -> out (40-wide, no relu)
    gemm_bf40_kernel<<<dim3(gemm_grid), b256, 0, stream>>>(
        hbA, 128, 128, hbC, 128, BhiA + P.l[4].boff, BloA + P.l[4].boff,
        cvecA + 512, dis, hwb, 256, N);
    agg40b_kernel<<<dim3(agg_grid), b256, 0, stream>>>(hwb, row_ptr, csr, dis, bo, outF, N);
}